// Round 1
// baseline (1766.710 us; speedup 1.0000x reference)
//
#include <hip/hip_runtime.h>
#include <math.h>

#define HD   256
#define FIN  32
#define NP   8192
#define PGH  4096
#define NLVL 15

__device__ __forceinline__ float lrelu(float x) { return x > 0.f ? x : 0.1f * x; }

// ---------------- pi kernel: prev_h = mlp(delay) ----------------
__global__ __launch_bounds__(256) void pi_kernel(
    const float* __restrict__ delay,
    const float* __restrict__ w1, const float* __restrict__ b1,
    const float* __restrict__ w2, const float* __restrict__ b2,
    float* __restrict__ outh)
{
    __shared__ float g1[32][132];
    const int tid = threadIdx.x;
    const int node0 = blockIdx.x * 32;

    for (int t = tid; t < 32 * 128; t += 256) {
        int i = t >> 7, jj = t & 127;
        float d = delay[node0 + i];
        g1[i][jj] = lrelu(d * w1[jj] + b1[jj]);
    }
    __syncthreads();

    const int j2 = (tid & 31) * 8;
    const int r2 = (tid >> 5) * 4;
    float acc[4][8];
#pragma unroll
    for (int ri = 0; ri < 4; ri++)
#pragma unroll
        for (int ci = 0; ci < 8; ci++) acc[ri][ci] = b2[j2 + ci];

#pragma unroll 4
    for (int k = 0; k < 128; k++) {
        float4 wa = *(const float4*)&w2[k * 256 + j2];
        float4 wb = *(const float4*)&w2[k * 256 + j2 + 4];
#pragma unroll
        for (int ri = 0; ri < 4; ri++) {
            float x = g1[r2 + ri][k];
            acc[ri][0] += x * wa.x; acc[ri][1] += x * wa.y; acc[ri][2] += x * wa.z; acc[ri][3] += x * wa.w;
            acc[ri][4] += x * wb.x; acc[ri][5] += x * wb.y; acc[ri][6] += x * wb.z; acc[ri][7] += x * wb.w;
        }
    }
#pragma unroll
    for (int ri = 0; ri < 4; ri++) {
        float4 va = make_float4(acc[ri][0], acc[ri][1], acc[ri][2], acc[ri][3]);
        float4 vb = make_float4(acc[ri][4], acc[ri][5], acc[ri][6], acc[ri][7]);
        *(float4*)&outh[(node0 + r2 + ri) * HD + j2]     = va;
        *(float4*)&outh[(node0 + r2 + ri) * HD + j2 + 4] = vb;
    }
}

// ---------------- per-level kernel: blocks 0..127 gate-half, 128..255 mod-half ----------------
__global__ __launch_bounds__(256) void level_kernel(
    const float* __restrict__ prevh, float* __restrict__ nexth,
    const float* __restrict__ feat, const float* __restrict__ bitpos,
    const int* __restrict__ srcidx,
    const float* __restrict__ g_w1, const float* __restrict__ g_b1,
    const float* __restrict__ g_w2, const float* __restrict__ g_b2,
    const float* __restrict__ m_w1, const float* __restrict__ m_b1,
    const float* __restrict__ m_w2, const float* __restrict__ m_b2,
    const float* __restrict__ t_w1, const float* __restrict__ t_b1,
    const float* __restrict__ t_w2, const float* __restrict__ t_b2,
    const float* __restrict__ p_w1, const float* __restrict__ p_b1,
    const float* __restrict__ p_w2, const float* __restrict__ p_b2,
    const float* __restrict__ av,
    int level, int apply_relu)
{
    __shared__ float x_lds[32][292];   // x tile (K up to 289)
    __shared__ float h1_lds[32][132];  // hidden-1 tile
    __shared__ int   src_lds[256];
    __shared__ float bp_lds[256];
    __shared__ float dstf_lds[32][32];
    __shared__ float zth1_lds[32][32];
    __shared__ float zt_lds[32][32];
    __shared__ float smdot_lds[256];
    __shared__ float alpha_lds[256];
    __shared__ float xbp_lds[32];
    __shared__ float av_lds[320];

    const int tid = threadIdx.x;
    const bool is_gate = (blockIdx.x < 128);
    const int node0 = is_gate ? (blockIdx.x * 32) : (PGH + (blockIdx.x - 128) * 32);

    src_lds[tid] = srcidx[(level * NP + node0) * 8 + tid];   // i=tid/8, f=tid%8

    if (is_gate) {
        // stage lvl_feat into x cols 256..287
        for (int t = tid; t < 1024; t += 256) {
            int i = t >> 5, k = t & 31;
            x_lds[i][256 + k] = feat[((level + 1) * NP + node0 + i) * FIN + k];
        }
        __syncthreads();
        // gather + per-channel softmax over fanin  (thread = channel)
        const int c = tid;
        for (int i = 0; i < 32; i++) {
            float mg[8]; float mx = -1e30f;
#pragma unroll
            for (int f = 0; f < 8; f++) {
                mg[f] = prevh[src_lds[i * 8 + f] * HD + c];
                mx = fmaxf(mx, mg[f]);
            }
            float s = 0.f, ws = 0.f;
#pragma unroll
            for (int f = 0; f < 8; f++) {
                float e = __expf(mg[f] - mx);
                s += e; ws += mg[f] * e;
            }
            x_lds[i][c] = ws / s;
        }
        __syncthreads();
    } else {
        bp_lds[tid] = bitpos[(level * NP + node0) * 8 + tid];
        for (int t = tid; t < 1024; t += 256) {
            int i = t >> 5, k = t & 31;
            dstf_lds[i][k] = feat[((level + 1) * NP + node0 + i) * FIN + k];
        }
        for (int t = tid; t < 320; t += 256) av_lds[t] = av[t];
        __syncthreads();

        // zt = mlp(dstf): stage 1
        for (int t = tid; t < 1024; t += 256) {
            int i = t >> 5, j = t & 31;
            float a = t_b1[j];
#pragma unroll 8
            for (int k = 0; k < 32; k++) a += dstf_lds[i][k] * t_w1[k * 32 + j];
            zth1_lds[i][j] = lrelu(a);
        }
        __syncthreads();
        for (int t = tid; t < 1024; t += 256) {
            int i = t >> 5, j = t & 31;
            float a = t_b2[j];
#pragma unroll 8
            for (int k = 0; k < 32; k++) a += zth1_lds[i][k] * t_w2[k * 32 + j];
            zt_lds[i][j] = a;
        }
        __syncthreads();

        // per-(node,fanin) thread: zp mlp + dot with av[32:64]; zt dot av[0:32]
        const int mi = tid >> 3;
        const float bpv = bp_lds[tid];
        float h1p[32];
#pragma unroll 8
        for (int j = 0; j < 32; j++) h1p[j] = lrelu(bpv * p_w1[j] + p_b1[j]);
        float zpdot = 0.f;
        for (int j = 0; j < 32; j++) {
            float a = p_b2[j];
#pragma unroll 8
            for (int k = 0; k < 32; k++) a += h1p[k] * p_w2[k * 32 + j];
            zpdot += a * av_lds[32 + j];
        }
        float ztdot = 0.f;
#pragma unroll 8
        for (int j = 0; j < 32; j++) ztdot += zt_lds[mi][j] * av_lds[j];

        // sm . av[64:320] per gathered row (wave-cooperative)
        const int wave = tid >> 6, lane = tid & 63;
        for (int rr = wave; rr < 256; rr += 4) {
            int row = src_lds[rr];
            float4 xv = *(const float4*)&prevh[row * HD + lane * 4];
            float pz = xv.x * av_lds[64 + lane * 4] + xv.y * av_lds[64 + lane * 4 + 1]
                     + xv.z * av_lds[64 + lane * 4 + 2] + xv.w * av_lds[64 + lane * 4 + 3];
#pragma unroll
            for (int off = 32; off > 0; off >>= 1) pz += __shfl_xor(pz, off);
            if (lane == 0) smdot_lds[rr] = pz;
        }
        __syncthreads();

        // alpha = softmax over fanin (8-lane groups)
        float logit = ztdot + zpdot + smdot_lds[tid];
        float mx = logit;
#pragma unroll
        for (int off = 1; off < 8; off <<= 1) mx = fmaxf(mx, __shfl_xor(mx, off));
        float e = __expf(logit - mx);
        float ssum = e;
#pragma unroll
        for (int off = 1; off < 8; off <<= 1) ssum += __shfl_xor(ssum, off);
        float alpha = e / ssum;
        alpha_lds[tid] = alpha;
        float ab = alpha * bpv;
#pragma unroll
        for (int off = 1; off < 8; off <<= 1) ab += __shfl_xor(ab, off);
        if ((tid & 7) == 0) xbp_lds[tid >> 3] = ab;
        __syncthreads();

        // neigh_m (channel-parallel) + assemble x = [neigh_m(256), bp_sum, dstf(32)]
        const int c = tid;
        for (int i = 0; i < 32; i++) {
            float a = 0.f;
#pragma unroll
            for (int f = 0; f < 8; f++)
                a += alpha_lds[i * 8 + f] * prevh[src_lds[i * 8 + f] * HD + c];
            x_lds[i][c] = a;
        }
        if (tid < 32) x_lds[tid][256] = xbp_lds[tid];
        for (int t = tid; t < 1024; t += 256) {
            int i = t >> 5, k = t & 31;
            x_lds[i][257 + k] = dstf_lds[i][k];
        }
        __syncthreads();
    }

    // ---------- GEMM1: (32 x K1) @ (K1 x 128) + b1, leaky ----------
    const float* w1 = is_gate ? g_w1 : m_w1;
    const float* b1 = is_gate ? g_b1 : m_b1;
    const int K1 = is_gate ? 288 : 289;
    {
        const int j = (tid & 31) * 4;
        const int r = (tid >> 5) * 4;
        float acc[4][4];
        float4 bv = *(const float4*)&b1[j];
#pragma unroll
        for (int ri = 0; ri < 4; ri++) {
            acc[ri][0] = bv.x; acc[ri][1] = bv.y; acc[ri][2] = bv.z; acc[ri][3] = bv.w;
        }
#pragma unroll 4
        for (int k = 0; k < K1; k++) {
            float4 w = *(const float4*)&w1[k * 128 + j];
#pragma unroll
            for (int ri = 0; ri < 4; ri++) {
                float x = x_lds[r + ri][k];
                acc[ri][0] += x * w.x; acc[ri][1] += x * w.y;
                acc[ri][2] += x * w.z; acc[ri][3] += x * w.w;
            }
        }
#pragma unroll
        for (int ri = 0; ri < 4; ri++) {
            float4 v = make_float4(lrelu(acc[ri][0]), lrelu(acc[ri][1]),
                                   lrelu(acc[ri][2]), lrelu(acc[ri][3]));
            *(float4*)&h1_lds[r + ri][j] = v;
        }
    }
    __syncthreads();

    // ---------- GEMM2: (32 x 128) @ (128 x 256) + b2 (+relu) ----------
    const float* w2 = is_gate ? g_w2 : m_w2;
    const float* b2 = is_gate ? g_b2 : m_b2;
    {
        const int j2 = (tid & 31) * 8;
        const int r2 = (tid >> 5) * 4;
        float acc[4][8];
#pragma unroll
        for (int ri = 0; ri < 4; ri++)
#pragma unroll
            for (int ci = 0; ci < 8; ci++) acc[ri][ci] = b2[j2 + ci];

#pragma unroll 4
        for (int k = 0; k < 128; k++) {
            float4 wa = *(const float4*)&w2[k * 256 + j2];
            float4 wb = *(const float4*)&w2[k * 256 + j2 + 4];
#pragma unroll
            for (int ri = 0; ri < 4; ri++) {
                float x = h1_lds[r2 + ri][k];
                acc[ri][0] += x * wa.x; acc[ri][1] += x * wa.y; acc[ri][2] += x * wa.z; acc[ri][3] += x * wa.w;
                acc[ri][4] += x * wb.x; acc[ri][5] += x * wb.y; acc[ri][6] += x * wb.z; acc[ri][7] += x * wb.w;
            }
        }
#pragma unroll
        for (int ri = 0; ri < 4; ri++) {
            if (apply_relu) {
#pragma unroll
                for (int ci = 0; ci < 8; ci++) acc[ri][ci] = fmaxf(acc[ri][ci], 0.f);
            }
            float4 va = make_float4(acc[ri][0], acc[ri][1], acc[ri][2], acc[ri][3]);
            float4 vb = make_float4(acc[ri][4], acc[ri][5], acc[ri][6], acc[ri][7]);
            *(float4*)&nexth[(node0 + r2 + ri) * HD + j2]     = va;
            *(float4*)&nexth[(node0 + r2 + ri) * HD + j2 + 4] = vb;
        }
    }
}

// ---------------- final kernel: h_global mlp + concat + out mlp ----------------
__global__ __launch_bounds__(256) void final_kernel(
    const float* __restrict__ prevh, const float* __restrict__ pofeat,
    const float* __restrict__ gl_w1, const float* __restrict__ gl_b1,
    const float* __restrict__ gl_w2, const float* __restrict__ gl_b2,
    const float* __restrict__ o_w1, const float* __restrict__ o_b1,
    const float* __restrict__ o_w2, const float* __restrict__ o_b2,
    float* __restrict__ out)
{
    __shared__ float x2[32][516];     // [prev_h(256) | h_global(256)]
    __shared__ float g1[32][132];
    __shared__ float h1o[32][260];
    __shared__ float ow2_lds[256];

    const int tid = threadIdx.x;
    const int node0 = blockIdx.x * 32;

    for (int t = tid; t < 2048; t += 256) {
        int i = t >> 6, c4 = (t & 63) * 4;
        *(float4*)&x2[i][c4] = *(const float4*)&prevh[(node0 + i) * HD + c4];
    }
    for (int t = tid; t < 4096; t += 256) {
        int i = t >> 7, jj = t & 127;
        float d = pofeat[node0 + i];
        g1[i][jj] = lrelu(d * gl_w1[jj] + gl_b1[jj]);
    }
    ow2_lds[tid] = o_w2[tid];
    __syncthreads();

    // h_global second layer: (32x128)@(128x256) -> x2 cols 256..511
    {
        const int j2 = (tid & 31) * 8;
        const int r2 = (tid >> 5) * 4;
        float acc[4][8];
#pragma unroll
        for (int ri = 0; ri < 4; ri++)
#pragma unroll
            for (int ci = 0; ci < 8; ci++) acc[ri][ci] = gl_b2[j2 + ci];
#pragma unroll 4
        for (int k = 0; k < 128; k++) {
            float4 wa = *(const float4*)&gl_w2[k * 256 + j2];
            float4 wb = *(const float4*)&gl_w2[k * 256 + j2 + 4];
#pragma unroll
            for (int ri = 0; ri < 4; ri++) {
                float x = g1[r2 + ri][k];
                acc[ri][0] += x * wa.x; acc[ri][1] += x * wa.y; acc[ri][2] += x * wa.z; acc[ri][3] += x * wa.w;
                acc[ri][4] += x * wb.x; acc[ri][5] += x * wb.y; acc[ri][6] += x * wb.z; acc[ri][7] += x * wb.w;
            }
        }
#pragma unroll
        for (int ri = 0; ri < 4; ri++) {
            *(float4*)&x2[r2 + ri][256 + j2]     = make_float4(acc[ri][0], acc[ri][1], acc[ri][2], acc[ri][3]);
            *(float4*)&x2[r2 + ri][256 + j2 + 4] = make_float4(acc[ri][4], acc[ri][5], acc[ri][6], acc[ri][7]);
        }
    }
    __syncthreads();

    // out layer 1: (32x512)@(512x256) + b, leaky
    {
        const int j2 = (tid & 31) * 8;
        const int r2 = (tid >> 5) * 4;
        float acc[4][8];
#pragma unroll
        for (int ri = 0; ri < 4; ri++)
#pragma unroll
            for (int ci = 0; ci < 8; ci++) acc[ri][ci] = o_b1[j2 + ci];
#pragma unroll 4
        for (int k = 0; k < 512; k++) {
            float4 wa = *(const float4*)&o_w1[k * 256 + j2];
            float4 wb = *(const float4*)&o_w1[k * 256 + j2 + 4];
#pragma unroll
            for (int ri = 0; ri < 4; ri++) {
                float x = x2[r2 + ri][k];
                acc[ri][0] += x * wa.x; acc[ri][1] += x * wa.y; acc[ri][2] += x * wa.z; acc[ri][3] += x * wa.w;
                acc[ri][4] += x * wb.x; acc[ri][5] += x * wb.y; acc[ri][6] += x * wb.z; acc[ri][7] += x * wb.w;
            }
        }
#pragma unroll
        for (int ri = 0; ri < 4; ri++) {
            float4 va = make_float4(lrelu(acc[ri][0]), lrelu(acc[ri][1]), lrelu(acc[ri][2]), lrelu(acc[ri][3]));
            float4 vb = make_float4(lrelu(acc[ri][4]), lrelu(acc[ri][5]), lrelu(acc[ri][6]), lrelu(acc[ri][7]));
            *(float4*)&h1o[r2 + ri][j2]     = va;
            *(float4*)&h1o[r2 + ri][j2 + 4] = vb;
        }
    }
    __syncthreads();

    // out layer 2: (32x256)@(256x1) + b
    {
        const int i = tid >> 3, seg = tid & 7;
        float s = 0.f;
#pragma unroll 8
        for (int j = seg * 32; j < seg * 32 + 32; j++) s += h1o[i][j] * ow2_lds[j];
#pragma unroll
        for (int off = 1; off < 8; off <<= 1) s += __shfl_xor(s, off);
        if (seg == 0) out[node0 + i] = s + o_b2[0];
    }
}

extern "C" void kernel_launch(void* const* d_in, const int* in_sizes, int n_in,
                              void* d_out, int out_size, void* d_ws, size_t ws_size,
                              hipStream_t stream)
{
    const float* delay    = (const float*)d_in[0];
    const float* feat     = (const float*)d_in[1];
    const float* bitpos   = (const float*)d_in[2];
    const float* pofeat   = (const float*)d_in[3];
    const int*   srcidx   = (const int*)  d_in[4];
    const float* pi_w1    = (const float*)d_in[5];
    const float* pi_b1    = (const float*)d_in[6];
    const float* pi_w2    = (const float*)d_in[7];
    const float* pi_b2    = (const float*)d_in[8];
    const float* gate_w1  = (const float*)d_in[9];
    const float* gate_b1  = (const float*)d_in[10];
    const float* gate_w2  = (const float*)d_in[11];
    const float* gate_b2  = (const float*)d_in[12];
    const float* mod_w1   = (const float*)d_in[13];
    const float* mod_b1   = (const float*)d_in[14];
    const float* mod_w2   = (const float*)d_in[15];
    const float* mod_b2   = (const float*)d_in[16];
    const float* type_w1  = (const float*)d_in[17];
    const float* type_b1  = (const float*)d_in[18];
    const float* type_w2  = (const float*)d_in[19];
    const float* type_b2  = (const float*)d_in[20];
    const float* pos_w1   = (const float*)d_in[21];
    const float* pos_b1   = (const float*)d_in[22];
    const float* pos_w2   = (const float*)d_in[23];
    const float* pos_b2   = (const float*)d_in[24];
    const float* attn_vec = (const float*)d_in[25];
    const float* glob_w1  = (const float*)d_in[26];
    const float* glob_b1  = (const float*)d_in[27];
    const float* glob_w2  = (const float*)d_in[28];
    const float* glob_b2  = (const float*)d_in[29];
    const float* out_w1   = (const float*)d_in[30];
    const float* out_b1   = (const float*)d_in[31];
    const float* out_w2   = (const float*)d_in[32];
    const float* out_b2   = (const float*)d_in[33];

    float* buf0 = (float*)d_ws;
    float* buf1 = buf0 + (size_t)NP * HD;

    pi_kernel<<<256, 256, 0, stream>>>(delay, pi_w1, pi_b1, pi_w2, pi_b2, buf0);

    for (int l = 0; l < NLVL; l++) {
        float* pv = (l & 1) ? buf1 : buf0;
        float* nx = (l & 1) ? buf0 : buf1;
        level_kernel<<<256, 256, 0, stream>>>(
            pv, nx, feat, bitpos, srcidx,
            gate_w1, gate_b1, gate_w2, gate_b2,
            mod_w1, mod_b1, mod_w2, mod_b2,
            type_w1, type_b1, type_w2, type_b2,
            pos_w1, pos_b1, pos_w2, pos_b2,
            attn_vec, l, (l != NLVL - 1) ? 1 : 0);
    }

    final_kernel<<<256, 256, 0, stream>>>(
        buf1, pofeat,
        glob_w1, glob_b1, glob_w2, glob_b2,
        out_w1, out_b1, out_w2, out_b2,
        (float*)d_out);
}

// Round 2
// 1524.856 us; speedup vs baseline: 1.1586x; 1.1586x over previous
//
#include <hip/hip_runtime.h>
#include <math.h>

#define HD   256
#define FIN  32
#define NP   8192
#define PGH  4096
#define NLVL 15
#define TN   16    // nodes per block tile

__device__ __forceinline__ float lrelu(float x) { return x > 0.f ? x : 0.1f * x; }

// ---------------- pi kernel: prev_h = mlp(delay) ----------------
__global__ __launch_bounds__(512, 4) void pi_kernel(
    const float* __restrict__ delay,
    const float* __restrict__ w1, const float* __restrict__ b1,
    const float* __restrict__ w2, const float* __restrict__ b2,
    float* __restrict__ outh)
{
    __shared__ float g1[TN][132];
    const int tid = threadIdx.x;
    const int node0 = blockIdx.x * TN;

    for (int t = tid; t < TN * 128; t += 512) {
        int i = t >> 7, jj = t & 127;
        float d = delay[node0 + i];
        g1[i][jj] = lrelu(d * w1[jj] + b1[jj]);
    }
    __syncthreads();

    const int j = (tid & 31) * 8;
    const int r = tid >> 5;
    float acc[8];
#pragma unroll
    for (int ci = 0; ci < 8; ci++) acc[ci] = b2[j + ci];

#pragma unroll 2
    for (int k = 0; k < 128; k += 4) {
        float4 xv = *(const float4*)&g1[r][k];
#pragma unroll
        for (int kk = 0; kk < 4; kk++) {
            float4 wa = *(const float4*)&w2[(k + kk) * 256 + j];
            float4 wb = *(const float4*)&w2[(k + kk) * 256 + j + 4];
            float x = (kk == 0) ? xv.x : (kk == 1) ? xv.y : (kk == 2) ? xv.z : xv.w;
            acc[0] += x * wa.x; acc[1] += x * wa.y; acc[2] += x * wa.z; acc[3] += x * wa.w;
            acc[4] += x * wb.x; acc[5] += x * wb.y; acc[6] += x * wb.z; acc[7] += x * wb.w;
        }
    }
    *(float4*)&outh[(node0 + r) * HD + j]     = make_float4(acc[0], acc[1], acc[2], acc[3]);
    *(float4*)&outh[(node0 + r) * HD + j + 4] = make_float4(acc[4], acc[5], acc[6], acc[7]);
}

// ---------------- per-level kernel: blocks 0..255 gate, 256..511 mod ----------------
__global__ __launch_bounds__(512, 4) void level_kernel(
    const float* __restrict__ prevh, float* __restrict__ nexth,
    const float* __restrict__ feat, const float* __restrict__ bitpos,
    const int* __restrict__ srcidx,
    const float* __restrict__ g_w1, const float* __restrict__ g_b1,
    const float* __restrict__ g_w2, const float* __restrict__ g_b2,
    const float* __restrict__ m_w1, const float* __restrict__ m_b1,
    const float* __restrict__ m_w2, const float* __restrict__ m_b2,
    const float* __restrict__ t_w1, const float* __restrict__ t_b1,
    const float* __restrict__ t_w2, const float* __restrict__ t_b2,
    const float* __restrict__ p_w1, const float* __restrict__ p_b1,
    const float* __restrict__ p_w2, const float* __restrict__ p_b2,
    const float* __restrict__ av,
    int level, int apply_relu)
{
    __shared__ float x_lds[TN][292];
    __shared__ float h1_lds[TN][132];
    __shared__ int   src_lds[TN * 8];
    __shared__ float bp_lds[TN * 8];
    __shared__ float dstf_lds[TN][32];
    __shared__ float ztt_lds[TN][32];
    __shared__ float zt_lds[TN][32];
    __shared__ float smdot_lds[TN * 8];
    __shared__ float alpha_lds[TN * 8];
    __shared__ float xbp_lds[TN];
    __shared__ float av_lds[320];

    const int tid = threadIdx.x;
    const bool is_gate = (blockIdx.x < 256);
    const int node0 = is_gate ? (blockIdx.x * TN) : (PGH + ((int)blockIdx.x - 256) * TN);

    if (tid < TN * 8) src_lds[tid] = srcidx[(level * NP + node0) * 8 + tid];

    if (is_gate) {
        for (int t = tid; t < TN * 32; t += 512) {
            int i = t >> 5, k = t & 31;
            x_lds[i][256 + k] = feat[((level + 1) * NP + node0 + i) * FIN + k];
        }
        __syncthreads();
        // gather + per-channel softmax over fanin
        for (int t = tid; t < TN * 256; t += 512) {
            int i = t >> 8, c = t & 255;
            const int* sp = &src_lds[i * 8];
            float mg[8]; float mx = -1e30f;
#pragma unroll
            for (int f = 0; f < 8; f++) {
                mg[f] = prevh[sp[f] * HD + c];
                mx = fmaxf(mx, mg[f]);
            }
            float s = 0.f, ws = 0.f;
#pragma unroll
            for (int f = 0; f < 8; f++) {
                float e = __expf(mg[f] - mx);
                s += e; ws += mg[f] * e;
            }
            x_lds[i][c] = ws / s;
        }
        __syncthreads();
    } else {
        if (tid < TN * 8) bp_lds[tid] = bitpos[(level * NP + node0) * 8 + tid];
        for (int t = tid; t < TN * 32; t += 512) {
            int i = t >> 5, k = t & 31;
            dstf_lds[i][k] = feat[((level + 1) * NP + node0 + i) * FIN + k];
        }
        if (tid < 320) av_lds[tid] = av[tid];
        __syncthreads();

        // zt = mlp(dstf): 512 tasks, one each
        {
            int i = tid >> 5, jj = tid & 31;
            float a = t_b1[jj];
#pragma unroll 8
            for (int k = 0; k < 32; k++) a += dstf_lds[i][k] * t_w1[k * 32 + jj];
            ztt_lds[i][jj] = lrelu(a);
        }
        __syncthreads();
        {
            int i = tid >> 5, jj = tid & 31;
            float a = t_b2[jj];
#pragma unroll 8
            for (int k = 0; k < 32; k++) a += ztt_lds[i][k] * t_w2[k * 32 + jj];
            zt_lds[i][jj] = a;
        }
        __syncthreads();

        // sm . av[64:320] per gathered row (wave-cooperative), 128 rows
        {
            int wave = tid >> 6, lane = tid & 63;
            for (int rr = wave; rr < TN * 8; rr += 8) {
                int row = src_lds[rr];
                float4 xv = *(const float4*)&prevh[row * HD + lane * 4];
                float pz = xv.x * av_lds[64 + lane * 4]     + xv.y * av_lds[64 + lane * 4 + 1]
                         + xv.z * av_lds[64 + lane * 4 + 2] + xv.w * av_lds[64 + lane * 4 + 3];
#pragma unroll
                for (int off = 32; off > 0; off >>= 1) pz += __shfl_xor(pz, off);
                if (lane == 0) smdot_lds[rr] = pz;
            }
        }

        // zp/zt logit partials: tid = i*32 + f*4 + jg
        {
            const int jg = tid & 3, f = (tid >> 2) & 7, i = tid >> 5;
            const float bpv = bp_lds[i * 8 + f];
            float h1p[32];
#pragma unroll 8
            for (int jj = 0; jj < 32; jj++) h1p[jj] = lrelu(bpv * p_w1[jj] + p_b1[jj]);
            float part = 0.f;
#pragma unroll
            for (int jj = jg * 8; jj < jg * 8 + 8; jj++) {
                float a = p_b2[jj];
#pragma unroll 8
                for (int k = 0; k < 32; k++) a += h1p[k] * p_w2[k * 32 + jj];
                part += a * av_lds[32 + jj];
                part += zt_lds[i][jj] * av_lds[jj];
            }
            part += __shfl_xor(part, 1);
            part += __shfl_xor(part, 2);
            __syncthreads();   // smdot_lds visible

            float logit = part + smdot_lds[i * 8 + f];
            float mx = logit;
#pragma unroll
            for (int off = 4; off <= 16; off <<= 1) mx = fmaxf(mx, __shfl_xor(mx, off));
            float e = __expf(logit - mx);
            float ssum = e;
#pragma unroll
            for (int off = 4; off <= 16; off <<= 1) ssum += __shfl_xor(ssum, off);
            float alpha = e / ssum;
            if (jg == 0) alpha_lds[i * 8 + f] = alpha;
            float ab = alpha * bpv;
#pragma unroll
            for (int off = 4; off <= 16; off <<= 1) ab += __shfl_xor(ab, off);
            if (((tid >> 2) & 7) == 0 && jg == 0) xbp_lds[i] = ab;
        }
        __syncthreads();

        // neigh_m + assemble x = [neigh_m(256), bp_sum, dstf(32)]
        for (int t = tid; t < TN * 256; t += 512) {
            int i = t >> 8, c = t & 255;
            const int* sp = &src_lds[i * 8];
            const float* ap = &alpha_lds[i * 8];
            float a = 0.f;
#pragma unroll
            for (int f = 0; f < 8; f++) a += ap[f] * prevh[sp[f] * HD + c];
            x_lds[i][c] = a;
        }
        if (tid < TN) x_lds[tid][256] = xbp_lds[tid];
        for (int t = tid; t < TN * 32; t += 512) {
            int i = t >> 5, k = t & 31;
            x_lds[i][257 + k] = dstf_lds[i][k];
        }
        __syncthreads();
    }

    // ---------- GEMM1: (TN x K1) @ (K1 x 128) + b1, leaky ----------
    const float* w1 = is_gate ? g_w1 : m_w1;
    const float* b1 = is_gate ? g_b1 : m_b1;
    {
        const int j = (tid & 31) * 4;
        const int r = tid >> 5;
        float4 bv = *(const float4*)&b1[j];
        float a0 = bv.x, a1 = bv.y, a2 = bv.z, a3 = bv.w;
#pragma unroll 2
        for (int k = 0; k < 288; k += 4) {
            float4 xv = *(const float4*)&x_lds[r][k];
            float4 w0 = *(const float4*)&w1[(k + 0) * 128 + j];
            float4 wv1 = *(const float4*)&w1[(k + 1) * 128 + j];
            float4 wv2 = *(const float4*)&w1[(k + 2) * 128 + j];
            float4 wv3 = *(const float4*)&w1[(k + 3) * 128 + j];
            a0 += xv.x * w0.x; a1 += xv.x * w0.y; a2 += xv.x * w0.z; a3 += xv.x * w0.w;
            a0 += xv.y * wv1.x; a1 += xv.y * wv1.y; a2 += xv.y * wv1.z; a3 += xv.y * wv1.w;
            a0 += xv.z * wv2.x; a1 += xv.z * wv2.y; a2 += xv.z * wv2.z; a3 += xv.z * wv2.w;
            a0 += xv.w * wv3.x; a1 += xv.w * wv3.y; a2 += xv.w * wv3.z; a3 += xv.w * wv3.w;
        }
        if (!is_gate) {
            float xb = x_lds[r][288];
            float4 wt = *(const float4*)&w1[288 * 128 + j];
            a0 += xb * wt.x; a1 += xb * wt.y; a2 += xb * wt.z; a3 += xb * wt.w;
        }
        *(float4*)&h1_lds[r][j] = make_float4(lrelu(a0), lrelu(a1), lrelu(a2), lrelu(a3));
    }
    __syncthreads();

    // ---------- GEMM2: (TN x 128) @ (128 x 256) + b2 (+relu) ----------
    const float* w2 = is_gate ? g_w2 : m_w2;
    const float* b2 = is_gate ? g_b2 : m_b2;
    {
        const int j = (tid & 31) * 8;
        const int r = tid >> 5;
        float acc[8];
#pragma unroll
        for (int ci = 0; ci < 8; ci++) acc[ci] = b2[j + ci];
#pragma unroll 2
        for (int k = 0; k < 128; k += 4) {
            float4 xv = *(const float4*)&h1_lds[r][k];
#pragma unroll
            for (int kk = 0; kk < 4; kk++) {
                float4 wa = *(const float4*)&w2[(k + kk) * 256 + j];
                float4 wb = *(const float4*)&w2[(k + kk) * 256 + j + 4];
                float x = (kk == 0) ? xv.x : (kk == 1) ? xv.y : (kk == 2) ? xv.z : xv.w;
                acc[0] += x * wa.x; acc[1] += x * wa.y; acc[2] += x * wa.z; acc[3] += x * wa.w;
                acc[4] += x * wb.x; acc[5] += x * wb.y; acc[6] += x * wb.z; acc[7] += x * wb.w;
            }
        }
        if (apply_relu) {
#pragma unroll
            for (int ci = 0; ci < 8; ci++) acc[ci] = fmaxf(acc[ci], 0.f);
        }
        *(float4*)&nexth[(node0 + r) * HD + j]     = make_float4(acc[0], acc[1], acc[2], acc[3]);
        *(float4*)&nexth[(node0 + r) * HD + j + 4] = make_float4(acc[4], acc[5], acc[6], acc[7]);
    }
}

// ---------------- final kernel ----------------
__global__ __launch_bounds__(512, 4) void final_kernel(
    const float* __restrict__ prevh, const float* __restrict__ pofeat,
    const float* __restrict__ gl_w1, const float* __restrict__ gl_b1,
    const float* __restrict__ gl_w2, const float* __restrict__ gl_b2,
    const float* __restrict__ o_w1, const float* __restrict__ o_b1,
    const float* __restrict__ o_w2, const float* __restrict__ o_b2,
    float* __restrict__ out)
{
    __shared__ float x2[TN][516];
    __shared__ float g1[TN][132];
    __shared__ float h1o[TN][260];
    __shared__ float ow2_lds[256];

    const int tid = threadIdx.x;
    const int node0 = blockIdx.x * TN;

    for (int t = tid; t < TN * 64; t += 512) {
        int i = t >> 6, c4 = (t & 63) * 4;
        *(float4*)&x2[i][c4] = *(const float4*)&prevh[(node0 + i) * HD + c4];
    }
    for (int t = tid; t < TN * 128; t += 512) {
        int i = t >> 7, jj = t & 127;
        float d = pofeat[node0 + i];
        g1[i][jj] = lrelu(d * gl_w1[jj] + gl_b1[jj]);
    }
    if (tid < 256) ow2_lds[tid] = o_w2[tid];
    __syncthreads();

    // h_global layer 2: (TN x 128)@(128 x 256) -> x2 cols 256..511
    {
        const int j = (tid & 31) * 8;
        const int r = tid >> 5;
        float acc[8];
#pragma unroll
        for (int ci = 0; ci < 8; ci++) acc[ci] = gl_b2[j + ci];
#pragma unroll 2
        for (int k = 0; k < 128; k += 4) {
            float4 xv = *(const float4*)&g1[r][k];
#pragma unroll
            for (int kk = 0; kk < 4; kk++) {
                float4 wa = *(const float4*)&gl_w2[(k + kk) * 256 + j];
                float4 wb = *(const float4*)&gl_w2[(k + kk) * 256 + j + 4];
                float x = (kk == 0) ? xv.x : (kk == 1) ? xv.y : (kk == 2) ? xv.z : xv.w;
                acc[0] += x * wa.x; acc[1] += x * wa.y; acc[2] += x * wa.z; acc[3] += x * wa.w;
                acc[4] += x * wb.x; acc[5] += x * wb.y; acc[6] += x * wb.z; acc[7] += x * wb.w;
            }
        }
        *(float4*)&x2[r][256 + j]     = make_float4(acc[0], acc[1], acc[2], acc[3]);
        *(float4*)&x2[r][256 + j + 4] = make_float4(acc[4], acc[5], acc[6], acc[7]);
    }
    __syncthreads();

    // out layer 1: (TN x 512)@(512 x 256) + b, leaky
    {
        const int j = (tid & 31) * 8;
        const int r = tid >> 5;
        float acc[8];
#pragma unroll
        for (int ci = 0; ci < 8; ci++) acc[ci] = o_b1[j + ci];
#pragma unroll 2
        for (int k = 0; k < 512; k += 4) {
            float4 xv = *(const float4*)&x2[r][k];
#pragma unroll
            for (int kk = 0; kk < 4; kk++) {
                float4 wa = *(const float4*)&o_w1[(k + kk) * 256 + j];
                float4 wb = *(const float4*)&o_w1[(k + kk) * 256 + j + 4];
                float x = (kk == 0) ? xv.x : (kk == 1) ? xv.y : (kk == 2) ? xv.z : xv.w;
                acc[0] += x * wa.x; acc[1] += x * wa.y; acc[2] += x * wa.z; acc[3] += x * wa.w;
                acc[4] += x * wb.x; acc[5] += x * wb.y; acc[6] += x * wb.z; acc[7] += x * wb.w;
            }
        }
#pragma unroll
        for (int ci = 0; ci < 8; ci++) acc[ci] = lrelu(acc[ci]);
        *(float4*)&h1o[r][j]     = make_float4(acc[0], acc[1], acc[2], acc[3]);
        *(float4*)&h1o[r][j + 4] = make_float4(acc[4], acc[5], acc[6], acc[7]);
    }
    __syncthreads();

    // out layer 2: (TN x 256)@(256 x 1) + b  — 32 lanes per row
    {
        const int i = tid >> 5, seg = tid & 31;
        float4 ha = *(const float4*)&h1o[i][seg * 8];
        float4 hb = *(const float4*)&h1o[i][seg * 8 + 4];
        float4 wa = *(const float4*)&ow2_lds[seg * 8];
        float4 wb = *(const float4*)&ow2_lds[seg * 8 + 4];
        float s = ha.x * wa.x + ha.y * wa.y + ha.z * wa.z + ha.w * wa.w
                + hb.x * wb.x + hb.y * wb.y + hb.z * wb.z + hb.w * wb.w;
#pragma unroll
        for (int off = 1; off < 32; off <<= 1) s += __shfl_xor(s, off);
        if (seg == 0) out[node0 + i] = s + o_b2[0];
    }
}

extern "C" void kernel_launch(void* const* d_in, const int* in_sizes, int n_in,
                              void* d_out, int out_size, void* d_ws, size_t ws_size,
                              hipStream_t stream)
{
    const float* delay    = (const float*)d_in[0];
    const float* feat     = (const float*)d_in[1];
    const float* bitpos   = (const float*)d_in[2];
    const float* pofeat   = (const float*)d_in[3];
    const int*   srcidx   = (const int*)  d_in[4];
    const float* pi_w1    = (const float*)d_in[5];
    const float* pi_b1    = (const float*)d_in[6];
    const float* pi_w2    = (const float*)d_in[7];
    const float* pi_b2    = (const float*)d_in[8];
    const float* gate_w1  = (const float*)d_in[9];
    const float* gate_b1  = (const float*)d_in[10];
    const float* gate_w2  = (const float*)d_in[11];
    const float* gate_b2  = (const float*)d_in[12];
    const float* mod_w1   = (const float*)d_in[13];
    const float* mod_b1   = (const float*)d_in[14];
    const float* mod_w2   = (const float*)d_in[15];
    const float* mod_b2   = (const float*)d_in[16];
    const float* type_w1  = (const float*)d_in[17];
    const float* type_b1  = (const float*)d_in[18];
    const float* type_w2  = (const float*)d_in[19];
    const float* type_b2  = (const float*)d_in[20];
    const float* pos_w1   = (const float*)d_in[21];
    const float* pos_b1   = (const float*)d_in[22];
    const float* pos_w2   = (const float*)d_in[23];
    const float* pos_b2   = (const float*)d_in[24];
    const float* attn_vec = (const float*)d_in[25];
    const float* glob_w1  = (const float*)d_in[26];
    const float* glob_b1  = (const float*)d_in[27];
    const float* glob_w2  = (const float*)d_in[28];
    const float* glob_b2  = (const float*)d_in[29];
    const float* out_w1   = (const float*)d_in[30];
    const float* out_b1   = (const float*)d_in[31];
    const float* out_w2   = (const float*)d_in[32];
    const float* out_b2   = (const float*)d_in[33];

    float* buf0 = (float*)d_ws;
    float* buf1 = buf0 + (size_t)NP * HD;

    pi_kernel<<<512, 512, 0, stream>>>(delay, pi_w1, pi_b1, pi_w2, pi_b2, buf0);

    for (int l = 0; l < NLVL; l++) {
        float* pv = (l & 1) ? buf1 : buf0;
        float* nx = (l & 1) ? buf0 : buf1;
        level_kernel<<<512, 512, 0, stream>>>(
            pv, nx, feat, bitpos, srcidx,
            gate_w1, gate_b1, gate_w2, gate_b2,
            mod_w1, mod_b1, mod_w2, mod_b2,
            type_w1, type_b1, type_w2, type_b2,
            pos_w1, pos_b1, pos_w2, pos_b2,
            attn_vec, l, (l != NLVL - 1) ? 1 : 0);
    }

    final_kernel<<<512, 512, 0, stream>>>(
        buf1, pofeat,
        glob_w1, glob_b1, glob_w2, glob_b2,
        out_w1, out_b1, out_w2, out_b2,
        (float*)d_out);
}

// Round 3
// 804.256 us; speedup vs baseline: 2.1967x; 1.8960x over previous
//
#include <hip/hip_runtime.h>
#include <math.h>

#define HD   256
#define FIN  32
#define NP   8192
#define PGH  4096
#define NLVL 15
#define TN   16    // nodes per block tile

__device__ __forceinline__ float lrelu(float x) { return x > 0.f ? x : 0.1f * x; }

// ---- 4-row x 4-col register micro-GEMM over K (K % 4 == 0) ----
// x rows come from LDS (wave-uniform broadcast), w streamed from global
__device__ __forceinline__ void gemm44(
    const float* xr0, const float* xr1, const float* xr2, const float* xr3,
    const float* __restrict__ w, int ldw, int j, int K, float acc[4][4])
{
#pragma unroll 2
    for (int k = 0; k < K; k += 4) {
        float4 x0 = *(const float4*)(xr0 + k);
        float4 x1 = *(const float4*)(xr1 + k);
        float4 x2 = *(const float4*)(xr2 + k);
        float4 x3 = *(const float4*)(xr3 + k);
        const float* wp = w + (size_t)k * ldw + j;
#define KK44(comp, off) { float4 wv = *(const float4*)(wp + (size_t)(off) * ldw); \
    acc[0][0] += x0.comp * wv.x; acc[0][1] += x0.comp * wv.y; acc[0][2] += x0.comp * wv.z; acc[0][3] += x0.comp * wv.w; \
    acc[1][0] += x1.comp * wv.x; acc[1][1] += x1.comp * wv.y; acc[1][2] += x1.comp * wv.z; acc[1][3] += x1.comp * wv.w; \
    acc[2][0] += x2.comp * wv.x; acc[2][1] += x2.comp * wv.y; acc[2][2] += x2.comp * wv.z; acc[2][3] += x2.comp * wv.w; \
    acc[3][0] += x3.comp * wv.x; acc[3][1] += x3.comp * wv.y; acc[3][2] += x3.comp * wv.z; acc[3][3] += x3.comp * wv.w; }
        KK44(x, 0) KK44(y, 1) KK44(z, 2) KK44(w, 3)
#undef KK44
    }
}

// ---- 4-row x 2-col register micro-GEMM ----
__device__ __forceinline__ void gemm42(
    const float* xr0, const float* xr1, const float* xr2, const float* xr3,
    const float* __restrict__ w, int ldw, int j, int K, float acc[4][2])
{
#pragma unroll 2
    for (int k = 0; k < K; k += 4) {
        float4 x0 = *(const float4*)(xr0 + k);
        float4 x1 = *(const float4*)(xr1 + k);
        float4 x2 = *(const float4*)(xr2 + k);
        float4 x3 = *(const float4*)(xr3 + k);
        const float* wp = w + (size_t)k * ldw + j;
#define KK42(comp, off) { float2 wv = *(const float2*)(wp + (size_t)(off) * ldw); \
    acc[0][0] += x0.comp * wv.x; acc[0][1] += x0.comp * wv.y; \
    acc[1][0] += x1.comp * wv.x; acc[1][1] += x1.comp * wv.y; \
    acc[2][0] += x2.comp * wv.x; acc[2][1] += x2.comp * wv.y; \
    acc[3][0] += x3.comp * wv.x; acc[3][1] += x3.comp * wv.y; }
        KK42(x, 0) KK42(y, 1) KK42(z, 2) KK42(w, 3)
#undef KK42
    }
}

// ---------------- pi kernel: prev_h = mlp(delay) ----------------
__global__ __launch_bounds__(256) void pi_kernel(
    const float* __restrict__ delay,
    const float* __restrict__ w1, const float* __restrict__ b1,
    const float* __restrict__ w2, const float* __restrict__ b2,
    float* __restrict__ outh)
{
    __shared__ float g1[TN][132];
    const int tid = threadIdx.x;
    const int node0 = blockIdx.x * TN;

    for (int t = tid; t < TN * 128; t += 256) {
        int i = t >> 7, jj = t & 127;
        float d = delay[node0 + i];
        g1[i][jj] = lrelu(d * w1[jj] + b1[jj]);
    }
    __syncthreads();

    const int j = (tid & 63) * 4;
    const int r = (tid >> 6) * 4;
    float acc[4][4];
    float4 bv = *(const float4*)&b2[j];
#pragma unroll
    for (int ri = 0; ri < 4; ri++) { acc[ri][0] = bv.x; acc[ri][1] = bv.y; acc[ri][2] = bv.z; acc[ri][3] = bv.w; }
    gemm44(&g1[r][0], &g1[r + 1][0], &g1[r + 2][0], &g1[r + 3][0], w2, 256, j, 128, acc);
#pragma unroll
    for (int ri = 0; ri < 4; ri++)
        *(float4*)&outh[(node0 + r + ri) * HD + j] = make_float4(acc[ri][0], acc[ri][1], acc[ri][2], acc[ri][3]);
}

// ---------------- per-level kernel: blocks 0..255 gate, 256..511 mod ----------------
__global__ __launch_bounds__(256) void level_kernel(
    const float* __restrict__ prevh, float* __restrict__ nexth,
    const float* __restrict__ feat, const float* __restrict__ bitpos,
    const int* __restrict__ srcidx,
    const float* __restrict__ g_w1, const float* __restrict__ g_b1,
    const float* __restrict__ g_w2, const float* __restrict__ g_b2,
    const float* __restrict__ m_w1, const float* __restrict__ m_b1,
    const float* __restrict__ m_w2, const float* __restrict__ m_b2,
    const float* __restrict__ t_w1, const float* __restrict__ t_b1,
    const float* __restrict__ t_w2, const float* __restrict__ t_b2,
    const float* __restrict__ p_w1, const float* __restrict__ p_b1,
    const float* __restrict__ p_w2, const float* __restrict__ p_b2,
    const float* __restrict__ av,
    int level, int apply_relu)
{
    __shared__ float x_lds[TN][292];
    __shared__ float h1_lds[TN][132];
    __shared__ int   src_lds[TN * 8];
    __shared__ float bp_lds[TN * 8];
    __shared__ float dstf_lds[TN][32];
    __shared__ float ztt_lds[TN][32];
    __shared__ float smdot_lds[TN * 8];
    __shared__ float alpha_lds[TN * 8];
    __shared__ float xbp_lds[TN];
    __shared__ float av_lds[320];
    __shared__ float tw2av_lds[32];
    __shared__ float pw2av_lds[32];
    __shared__ float bias_av[2];

    const int tid = threadIdx.x;
    const bool is_gate = (blockIdx.x < 256);
    const int node0 = is_gate ? (blockIdx.x * TN) : (PGH + ((int)blockIdx.x - 256) * TN);

    if (tid < TN * 8) src_lds[tid] = srcidx[(level * NP + node0) * 8 + tid];

    if (is_gate) {
        for (int t = tid; t < TN * 32; t += 256) {
            int i = t >> 5, k = t & 31;
            x_lds[i][256 + k] = feat[((level + 1) * NP + node0 + i) * FIN + k];
        }
        __syncthreads();
        // gather + per-channel softmax over fanin: iteration s handles node s, c = tid
        for (int s = 0; s < TN; s++) {
            const int* sp = &src_lds[s * 8];
            float mg[8]; float mx = -1e30f;
#pragma unroll
            for (int f = 0; f < 8; f++) {
                mg[f] = prevh[sp[f] * HD + tid];
                mx = fmaxf(mx, mg[f]);
            }
            float ssum = 0.f, ws = 0.f;
#pragma unroll
            for (int f = 0; f < 8; f++) {
                float e = __expf(mg[f] - mx);
                ssum += e; ws += mg[f] * e;
            }
            x_lds[s][tid] = ws / ssum;
        }
        __syncthreads();
    } else {
        if (tid < TN * 8) bp_lds[tid] = bitpos[(level * NP + node0) * 8 + tid];
        for (int t = tid; t < TN * 32; t += 256) {
            int i = t >> 5, k = t & 31;
            dstf_lds[i][k] = feat[((level + 1) * NP + node0 + i) * FIN + k];
        }
        for (int t = tid; t < 320; t += 256) av_lds[t] = av[t];
        __syncthreads();

        // ztt = lrelu(dstf @ t_w1 + t_b1)
        for (int t = tid; t < TN * 32; t += 256) {
            int i = t >> 5, jj = t & 31;
            float a = t_b1[jj];
#pragma unroll 8
            for (int k = 0; k < 32; k++) a += dstf_lds[i][k] * t_w1[k * 32 + jj];
            ztt_lds[i][jj] = lrelu(a);
        }
        // fold attn_vec through second MLP layers (exact linear reassociation)
        if (tid < 32) {
            float s = 0.f;
#pragma unroll 8
            for (int jj = 0; jj < 32; jj++) s += t_w2[tid * 32 + jj] * av_lds[jj];
            tw2av_lds[tid] = s;
        } else if (tid < 64) {
            int k = tid - 32;
            float s = 0.f;
#pragma unroll 8
            for (int jj = 0; jj < 32; jj++) s += p_w2[k * 32 + jj] * av_lds[32 + jj];
            pw2av_lds[k] = s;
        } else if (tid == 64) {
            float s = 0.f;
#pragma unroll 8
            for (int jj = 0; jj < 32; jj++) s += t_b2[jj] * av_lds[jj];
            bias_av[0] = s;
        } else if (tid == 65) {
            float s = 0.f;
#pragma unroll 8
            for (int jj = 0; jj < 32; jj++) s += p_b2[jj] * av_lds[32 + jj];
            bias_av[1] = s;
        }
        // sm . av[64:320] per gathered row (wave-cooperative), 128 rows / 4 waves
        {
            int wave = tid >> 6, lane = tid & 63;
            for (int rr = wave; rr < TN * 8; rr += 4) {
                int row = src_lds[rr];
                float4 xv = *(const float4*)&prevh[row * HD + lane * 4];
                float pz = xv.x * av_lds[64 + lane * 4]     + xv.y * av_lds[64 + lane * 4 + 1]
                         + xv.z * av_lds[64 + lane * 4 + 2] + xv.w * av_lds[64 + lane * 4 + 3];
#pragma unroll
                for (int off = 32; off > 0; off >>= 1) pz += __shfl_xor(pz, off);
                if (lane == 0) smdot_lds[rr] = pz;
            }
        }
        __syncthreads();

        // logits + softmax over fanin: tid = i*16 + f*2 + jg
        {
            const int jg = tid & 1, f = (tid >> 1) & 7, i = tid >> 4;
            const float bpv = bp_lds[i * 8 + f];
            float part = 0.f;
            const int k0 = jg * 16;
#pragma unroll
            for (int k = k0; k < k0 + 16; k++) {
                float h1pk = lrelu(bpv * p_w1[k] + p_b1[k]);
                part += h1pk * pw2av_lds[k];
                part += ztt_lds[i][k] * tw2av_lds[k];
            }
            part += __shfl_xor(part, 1);
            float logit = part + bias_av[0] + bias_av[1] + smdot_lds[i * 8 + f];
            float mx = logit;
            mx = fmaxf(mx, __shfl_xor(mx, 2));
            mx = fmaxf(mx, __shfl_xor(mx, 4));
            mx = fmaxf(mx, __shfl_xor(mx, 8));
            float e = __expf(logit - mx);
            float ssum = e;
            ssum += __shfl_xor(ssum, 2);
            ssum += __shfl_xor(ssum, 4);
            ssum += __shfl_xor(ssum, 8);
            float alpha = e / ssum;
            if (jg == 0) alpha_lds[i * 8 + f] = alpha;
            float ab = alpha * bpv;
            ab += __shfl_xor(ab, 2);
            ab += __shfl_xor(ab, 4);
            ab += __shfl_xor(ab, 8);
            if ((tid & 15) == 0) xbp_lds[i] = ab;
        }
        __syncthreads();

        // neigh_m + assemble x = [neigh_m(256), bp_sum, dstf(32)]
        for (int s = 0; s < TN; s++) {
            const int* sp = &src_lds[s * 8];
            const float* ap = &alpha_lds[s * 8];
            float a = 0.f;
#pragma unroll
            for (int f = 0; f < 8; f++) a += ap[f] * prevh[sp[f] * HD + tid];
            x_lds[s][tid] = a;
        }
        if (tid < TN) x_lds[tid][256] = xbp_lds[tid];
        for (int t = tid; t < TN * 32; t += 256) {
            int i = t >> 5, k = t & 31;
            x_lds[i][257 + k] = dstf_lds[i][k];
        }
        __syncthreads();
    }

    // ---------- GEMM1: (TN x K1) @ (K1 x 128) + b1, leaky ----------
    const float* w1 = is_gate ? g_w1 : m_w1;
    const float* b1 = is_gate ? g_b1 : m_b1;
    {
        const int j = (tid & 63) * 2;
        const int r = (tid >> 6) * 4;
        float acc[4][2];
        float2 bv = *(const float2*)&b1[j];
#pragma unroll
        for (int ri = 0; ri < 4; ri++) { acc[ri][0] = bv.x; acc[ri][1] = bv.y; }
        gemm42(&x_lds[r][0], &x_lds[r + 1][0], &x_lds[r + 2][0], &x_lds[r + 3][0],
               w1, 128, j, 288, acc);
        if (!is_gate) {
            float2 wt = *(const float2*)&w1[288 * 128 + j];
#pragma unroll
            for (int ri = 0; ri < 4; ri++) {
                float xb = x_lds[r + ri][288];
                acc[ri][0] += xb * wt.x; acc[ri][1] += xb * wt.y;
            }
        }
#pragma unroll
        for (int ri = 0; ri < 4; ri++)
            *(float2*)&h1_lds[r + ri][j] = make_float2(lrelu(acc[ri][0]), lrelu(acc[ri][1]));
    }
    __syncthreads();

    // ---------- GEMM2: (TN x 128) @ (128 x 256) + b2 (+relu) ----------
    const float* w2 = is_gate ? g_w2 : m_w2;
    const float* b2 = is_gate ? g_b2 : m_b2;
    {
        const int j = (tid & 63) * 4;
        const int r = (tid >> 6) * 4;
        float acc[4][4];
        float4 bv = *(const float4*)&b2[j];
#pragma unroll
        for (int ri = 0; ri < 4; ri++) { acc[ri][0] = bv.x; acc[ri][1] = bv.y; acc[ri][2] = bv.z; acc[ri][3] = bv.w; }
        gemm44(&h1_lds[r][0], &h1_lds[r + 1][0], &h1_lds[r + 2][0], &h1_lds[r + 3][0],
               w2, 256, j, 128, acc);
#pragma unroll
        for (int ri = 0; ri < 4; ri++) {
            if (apply_relu) {
#pragma unroll
                for (int ci = 0; ci < 4; ci++) acc[ri][ci] = fmaxf(acc[ri][ci], 0.f);
            }
            *(float4*)&nexth[(node0 + r + ri) * HD + j] =
                make_float4(acc[ri][0], acc[ri][1], acc[ri][2], acc[ri][3]);
        }
    }
}

// ---------------- final kernel ----------------
__global__ __launch_bounds__(256) void final_kernel(
    const float* __restrict__ prevh, const float* __restrict__ pofeat,
    const float* __restrict__ gl_w1, const float* __restrict__ gl_b1,
    const float* __restrict__ gl_w2, const float* __restrict__ gl_b2,
    const float* __restrict__ o_w1, const float* __restrict__ o_b1,
    const float* __restrict__ o_w2, const float* __restrict__ o_b2,
    float* __restrict__ out)
{
    __shared__ float x2[TN][516];
    __shared__ float g1[TN][132];
    __shared__ float h1o[TN][260];
    __shared__ float ow2_lds[256];

    const int tid = threadIdx.x;
    const int node0 = blockIdx.x * TN;

    for (int t = tid; t < TN * 64; t += 256) {
        int i = t >> 6, c4 = (t & 63) * 4;
        *(float4*)&x2[i][c4] = *(const float4*)&prevh[(node0 + i) * HD + c4];
    }
    for (int t = tid; t < TN * 128; t += 256) {
        int i = t >> 7, jj = t & 127;
        float d = pofeat[node0 + i];
        g1[i][jj] = lrelu(d * gl_w1[jj] + gl_b1[jj]);
    }
    ow2_lds[tid] = o_w2[tid];
    __syncthreads();

    const int j = (tid & 63) * 4;
    const int r = (tid >> 6) * 4;

    // h_global layer 2 -> x2 cols 256..511
    {
        float acc[4][4];
        float4 bv = *(const float4*)&gl_b2[j];
#pragma unroll
        for (int ri = 0; ri < 4; ri++) { acc[ri][0] = bv.x; acc[ri][1] = bv.y; acc[ri][2] = bv.z; acc[ri][3] = bv.w; }
        gemm44(&g1[r][0], &g1[r + 1][0], &g1[r + 2][0], &g1[r + 3][0], gl_w2, 256, j, 128, acc);
#pragma unroll
        for (int ri = 0; ri < 4; ri++)
            *(float4*)&x2[r + ri][256 + j] = make_float4(acc[ri][0], acc[ri][1], acc[ri][2], acc[ri][3]);
    }
    __syncthreads();

    // out layer 1: (TN x 512)@(512 x 256) + b, leaky
    {
        float acc[4][4];
        float4 bv = *(const float4*)&o_b1[j];
#pragma unroll
        for (int ri = 0; ri < 4; ri++) { acc[ri][0] = bv.x; acc[ri][1] = bv.y; acc[ri][2] = bv.z; acc[ri][3] = bv.w; }
        gemm44(&x2[r][0], &x2[r + 1][0], &x2[r + 2][0], &x2[r + 3][0], o_w1, 256, j, 512, acc);
#pragma unroll
        for (int ri = 0; ri < 4; ri++)
            *(float4*)&h1o[r + ri][j] = make_float4(lrelu(acc[ri][0]), lrelu(acc[ri][1]),
                                                    lrelu(acc[ri][2]), lrelu(acc[ri][3]));
    }
    __syncthreads();

    // out layer 2: (TN x 256)@(256 x 1) + b  — 16 lanes per row
    {
        const int i = tid >> 4, seg = tid & 15;
        const float* hp = &h1o[i][seg * 16];
        const float* wp = &ow2_lds[seg * 16];
        float s = 0.f;
#pragma unroll
        for (int q = 0; q < 4; q++) {
            float4 hv = *(const float4*)(hp + q * 4);
            float4 wv = *(const float4*)(wp + q * 4);
            s += hv.x * wv.x + hv.y * wv.y + hv.z * wv.z + hv.w * wv.w;
        }
        s += __shfl_xor(s, 1);
        s += __shfl_xor(s, 2);
        s += __shfl_xor(s, 4);
        s += __shfl_xor(s, 8);
        if (seg == 0) out[node0 + i] = s + o_b2[0];
    }
}

extern "C" void kernel_launch(void* const* d_in, const int* in_sizes, int n_in,
                              void* d_out, int out_size, void* d_ws, size_t ws_size,
                              hipStream_t stream)
{
    const float* delay    = (const float*)d_in[0];
    const float* feat     = (const float*)d_in[1];
    const float* bitpos   = (const float*)d_in[2];
    const float* pofeat   = (const float*)d_in[3];
    const int*   srcidx   = (const int*)  d_in[4];
    const float* pi_w1    = (const float*)d_in[5];
    const float* pi_b1    = (const float*)d_in[6];
    const float* pi_w2    = (const float*)d_in[7];
    const float* pi_b2    = (const float*)d_in[8];
    const float* gate_w1  = (const float*)d_in[9];
    const float* gate_b1  = (const float*)d_in[10];
    const float* gate_w2  = (const float*)d_in[11];
    const float* gate_b2  = (const float*)d_in[12];
    const float* mod_w1   = (const float*)d_in[13];
    const float* mod_b1   = (const float*)d_in[14];
    const float* mod_w2   = (const float*)d_in[15];
    const float* mod_b2   = (const float*)d_in[16];
    const float* type_w1  = (const float*)d_in[17];
    const float* type_b1  = (const float*)d_in[18];
    const float* type_w2  = (const float*)d_in[19];
    const float* type_b2  = (const float*)d_in[20];
    const float* pos_w1   = (const float*)d_in[21];
    const float* pos_b1   = (const float*)d_in[22];
    const float* pos_w2   = (const float*)d_in[23];
    const float* pos_b2   = (const float*)d_in[24];
    const float* attn_vec = (const float*)d_in[25];
    const float* glob_w1  = (const float*)d_in[26];
    const float* glob_b1  = (const float*)d_in[27];
    const float* glob_w2  = (const float*)d_in[28];
    const float* glob_b2  = (const float*)d_in[29];
    const float* out_w1   = (const float*)d_in[30];
    const float* out_b1   = (const float*)d_in[31];
    const float* out_w2   = (const float*)d_in[32];
    const float* out_b2   = (const float*)d_in[33];

    float* buf0 = (float*)d_ws;
    float* buf1 = buf0 + (size_t)NP * HD;

    pi_kernel<<<NP / TN, 256, 0, stream>>>(delay, pi_w1, pi_b1, pi_w2, pi_b2, buf0);

    for (int l = 0; l < NLVL; l++) {
        float* pv = (l & 1) ? buf1 : buf0;
        float* nx = (l & 1) ? buf0 : buf1;
        level_kernel<<<NP / TN, 256, 0, stream>>>(
            pv, nx, feat, bitpos, srcidx,
            gate_w1, gate_b1, gate_w2, gate_b2,
            mod_w1, mod_b1, mod_w2, mod_b2,
            type_w1, type_b1, type_w2, type_b2,
            pos_w1, pos_b1, pos_w2, pos_b2,
            attn_vec, l, (l != NLVL - 1) ? 1 : 0);
    }

    final_kernel<<<NP / TN, 256, 0, stream>>>(
        buf1, pofeat,
        glob_w1, glob_b1, glob_w2, glob_b2,
        out_w1, out_b1, out_w2, out_b2,
        (float*)d_out);
}